// Round 13
// baseline (186.916 us; speedup 1.0000x reference)
//
#include <hip/hip_runtime.h>
#include <hip/hip_bf16.h>
#include <cmath>

#define T_SEQ 2048
#define D_MODEL 1024
#define NHEAD 16
#define DK 64

typedef short bf16x8 __attribute__((ext_vector_type(8)));
typedef float f32x4 __attribute__((ext_vector_type(4)));
typedef float f32x16 __attribute__((ext_vector_type(16)));
typedef unsigned uint2v __attribute__((ext_vector_type(2)));

union U8 { unsigned u[4]; bf16x8 v; };

#define VMCNT(n) asm volatile("s_waitcnt vmcnt(" #n ")" ::: "memory")
#define BAR() __builtin_amdgcn_s_barrier()
#define SFENCE() __builtin_amdgcn_sched_barrier(0)

// RNE float -> bf16 (finite inputs only)
__device__ __forceinline__ short f2b(float f) {
    unsigned u = __builtin_bit_cast(unsigned, f);
    unsigned r = (u + 0x7FFFu + ((u >> 16) & 1u)) >> 16;
    return (short)r;
}

// async global->LDS, 16B per lane; lds base wave-uniform (HW adds lane*16)
__device__ __forceinline__ void gll16(const void* g, void* l) {
    __builtin_amdgcn_global_load_lds(
        (__attribute__((address_space(1))) void*)g,
        (__attribute__((address_space(3))) void*)l, 16, 0, 0);
}

// XOR-swizzled LDS frag read: row stride 128B, 16B chunk index 0..7
__device__ __forceinline__ bf16x8 lds_frag(const short* base, int row, int chunk) {
    return *reinterpret_cast<const bf16x8*>(
        (const char*)base + row * 128 + ((chunk * 16) ^ ((row & 7) << 4)));
}

__device__ __forceinline__ unsigned pkbf16(float a, float b) {
    unsigned r;
    asm("v_cvt_pk_bf16_f32 %0, %1, %2" : "=v"(r) : "v"(a), "v"(b));
    return r;
}
__device__ __forceinline__ void pl32swap(unsigned& a, unsigned& b) {
    uint2v r = __builtin_amdgcn_permlane32_swap(a, b, false, false);
    a = r.x; b = r.y;
}

// ====== fused fp32->bf16 convert into TILED layouts + RoPE table (one launch) ======
__global__ __launch_bounds__(256) void cvt_all(const float* __restrict__ x,
                                               const float* __restrict__ wq,
                                               const float* __restrict__ wo,
                                               const int* __restrict__ pos,
                                               short* __restrict__ xb,
                                               short* __restrict__ wqb,
                                               short* __restrict__ wob,
                                               float* __restrict__ ct,
                                               float* __restrict__ st) {
    int i = blockIdx.x * 256 + threadIdx.x;
    if (i >= 1048576) {                 // RoPE table: 131072 entries
        int j = i - 1048576;
        int bt = j >> 5, n = j & 31;
        float p = (float)pos[bt];
        float invf = expf((float)n * (-2.0f / (float)DK) * 9.210340371976184f);
        float s, c;
        sincosf(p * invf, &s, &c);
        ct[j] = c; st[j] = s;
        return;
    }
    const float* src;
    short* dst;
    int srcoff, c;
    if (i < 524288) {                 // xb: 32 rb x 32 kb tiles (128-row)
        c = i;
        int tile = c >> 9, cc = c & 511;
        int kblk = cc >> 7, row = cc & 127;
        int rb = tile >> 5, kb = tile & 31;
        srcoff = (rb * 128 + row) * D_MODEL + kb * 32 + kblk * 8;
        src = x; dst = xb;
    } else if (i < 917504) {          // wqb: 24 nb x 32 kb tiles (128-row)
        c = i - 524288;
        int tile = c >> 9, cc = c & 511;
        int kblk = cc >> 7, row = cc & 127;
        int rb = tile >> 5, kb = tile & 31;
        srcoff = (rb * 128 + row) * D_MODEL + kb * 32 + kblk * 8;
        src = wq; dst = wqb;
    } else {                          // wob: 16 nb x 32 kb tiles (64-row)
        c = i - 917504;
        int tile = c >> 8, cc = c & 255;
        int kblk = cc >> 6, row = cc & 63;
        int nb = tile >> 5, kb = tile & 31;
        srcoff = (nb * 64 + row) * D_MODEL + kb * 32 + kblk * 8;
        src = wo; dst = wob;
    }
    float4 a = *reinterpret_cast<const float4*>(src + srcoff);
    float4 b = *reinterpret_cast<const float4*>(src + srcoff + 4);
    bf16x8 v;
    v[0] = f2b(a.x); v[1] = f2b(a.y); v[2] = f2b(a.z); v[3] = f2b(a.w);
    v[4] = f2b(b.x); v[5] = f2b(b.y); v[6] = f2b(b.z); v[7] = f2b(b.w);
    reinterpret_cast<bf16x8*>(dst)[c] = v;
}

// ---------------- GEMM1: qkv = x * W_qkv^T, fused RoPE, scatter ----------------
// V written in per-(head,kvtile) tiles [ch(8)][d(64)][8] for coalesced PV loads.
__global__ __launch_bounds__(256, 3) void gemm_qkv(const short* __restrict__ xb,
                                                   const short* __restrict__ wb,
                                                   const float* __restrict__ ct,
                                                   const float* __restrict__ st,
                                                   short* __restrict__ Qo,
                                                   short* __restrict__ Ko,
                                                   short* __restrict__ Vt) {
    __shared__ short SM[3][8192];   // [buf][ A:0..4096 | B:4096..8192 ]
    const int tid = threadIdx.x;
    const int w = tid >> 6, l = tid & 63, lg = l >> 4, li = l & 15;
    const int wr = w >> 1, wc = w & 1;
    const int bn = blockIdx.x * 128, bm = blockIdx.y * 128;

    const short* pA = xb + (size_t)blockIdx.y * 32 * 4096 + (w * 128 + l) * 8;
    const short* pB = wb + (size_t)blockIdx.x * 32 * 4096 + (w * 128 + l) * 8;

    f32x4 zero = {0.f, 0.f, 0.f, 0.f};
    f32x4 acc[4][4];
#pragma unroll
    for (int m = 0; m < 4; ++m)
#pragma unroll
        for (int n = 0; n < 4; ++n) acc[m][n] = zero;

#define GSTAGE(buf, t_)                                               \
    do {                                                              \
        const size_t ko = (size_t)(t_) * 4096;                        \
        gll16(pA + ko,       &SM[buf][w * 1024]);                     \
        gll16(pA + ko + 512, &SM[buf][w * 1024 + 512]);               \
        gll16(pB + ko,       &SM[buf][4096 + w * 1024]);              \
        gll16(pB + ko + 512, &SM[buf][4096 + w * 1024 + 512]);        \
    } while (0)

    GSTAGE(0, 0);
    GSTAGE(1, 1);

    for (int t = 0; t < 32; ++t) {
        if (t < 31) { VMCNT(4); } else { VMCNT(0); }
        BAR();
        SFENCE();
        if (t + 2 < 32) GSTAGE((t + 2) % 3, t + 2);
        const short* Ac = &SM[t % 3][0];
        const short* Bc = &SM[t % 3][4096];
        bf16x8 a[4], b[4];
#pragma unroll
        for (int m = 0; m < 4; ++m)
            a[m] = *reinterpret_cast<const bf16x8*>(&Ac[lg * 1024 + (wr * 64 + m * 16 + li) * 8]);
#pragma unroll
        for (int n = 0; n < 4; ++n)
            b[n] = *reinterpret_cast<const bf16x8*>(&Bc[lg * 1024 + (wc * 64 + n * 16 + li) * 8]);
        __builtin_amdgcn_s_setprio(1);
#pragma unroll
        for (int m = 0; m < 4; ++m)
#pragma unroll
            for (int n = 0; n < 4; ++n)
                acc[m][n] = __builtin_amdgcn_mfma_f32_16x16x32_bf16(a[m], b[n], acc[m][n], 0, 0, 0);
        __builtin_amdgcn_s_setprio(0);
    }
#undef GSTAGE

    const int which = bn >> 10;                 // 0:q 1:k 2:v
    const int h = ((bn >> 6) + wc) & 15;
    if (which == 2) {
        // V: transpose via per-wave 8KB LDS scratch, write [ch][d][8] tiles
        __syncthreads();
        short* scr = &SM[0][0] + w * 4096;      // [d(64)][t(64)] swizzled, 8KB
#pragma unroll
        for (int n = 0; n < 4; ++n)
#pragma unroll
            for (int m = 0; m < 4; ++m)
#pragma unroll
                for (int rp = 0; rp < 2; ++rp) {
                    int d = n * 16 + li;
                    int t64 = m * 16 + lg * 4 + rp * 2;
                    unsigned pk = pkbf16(acc[m][n][rp * 2], acc[m][n][rp * 2 + 1]);
                    *reinterpret_cast<unsigned*>(
                        (char*)scr + ((d * 128 + t64 * 2) ^ ((d & 7) << 4))) = pk;
                }
        const int mi0 = bm + wr * 64;
        const int b0 = mi0 >> 11, t0 = mi0 & (T_SEQ - 1);
        const int kvt = t0 >> 6;
        short* vbase = Vt + ((size_t)(b0 * NHEAD + h) * 32 + kvt) * 4096;
        const int ch = l >> 3;
#pragma unroll
        for (int db = 0; db < 8; ++db) {
            int d = db * 8 + (l & 7);
            bf16x8 v = *reinterpret_cast<const bf16x8*>(
                (char*)scr + ((d * 128 + ch * 16) ^ ((d & 7) << 4)));
            *reinterpret_cast<bf16x8*>(vbase + ch * 512 + d * 8) = v;
        }
    } else {
#pragma unroll
        for (int n = 0; n < 4; ++n) {
            const int d = n * 16 + li;
#pragma unroll
            for (int m = 0; m < 4; ++m)
#pragma unroll
                for (int r = 0; r < 4; ++r) {
                    const int mi = bm + wr * 64 + m * 16 + lg * 4 + r;
                    const int b_ = mi >> 11, tt = mi & (T_SEQ - 1);
                    float v = acc[m][n][r];
                    float vp = __shfl_xor(v, 1);
                    int nn = n * 8 + (li >> 1);
                    float c = ct[(size_t)mi * 32 + nn];
                    float s = st[(size_t)mi * 32 + nn];
                    float o = (d & 1) ? (v * c + vp * s) : (v * c - vp * s);
                    if (which == 0) o *= 0.18033688011112042f;
                    short* dst = (which == 0) ? Qo : Ko;
                    dst[((size_t)((b_ * NHEAD + h) * T_SEQ + tt)) * DK + d] = f2b(o);
                }
        }
    }
}

// ------- flash attention (causal), software-pipelined, 2-wave blocks, LPT -------
// 1024 blocks x 128 thr: bh = bid&31 (4 heads/XCD), qt = 31-(bid>>5) (longest first).
// Wave w owns q rows [qt*64 + 32w, +32); both waves iterate all ntb = qt+1 KV tiles.
// QK(t) | PV(t-1) | softmax(t) overlap; V frags in registers from tiled Vt; K in
// 16 KB double-buffered LDS.
__global__ __launch_bounds__(128, 4) void attn(const short* __restrict__ Q,
                                               const short* __restrict__ K,
                                               const short* __restrict__ Vt,
                                               short* __restrict__ Cc) {
    __shared__ short Kls[2][4096];

    const int bid = blockIdx.x;
    const int bh = bid & 31;
    const int qt = 31 - (bid >> 5);
    const int ntb = qt + 1;

    const int tid = threadIdx.x;          // 0..127
    const int w = tid >> 6, l = tid & 63;
    const int l31 = l & 31, hi = l >> 5, hi4 = hi * 4, hi8 = hi * 8;
    const int q0w = qt * 64 + w * 32;

    const short* Qh = Q + (size_t)bh * T_SEQ * DK;
    const short* Kh = K + (size_t)bh * T_SEQ * DK;
    const short* Vh = Vt + (size_t)bh * 32 * 4096;

    bf16x8 qf[4];
#pragma unroll
    for (int ks = 0; ks < 4; ++ks)
        qf[ks] = *reinterpret_cast<const bf16x8*>(&Qh[(size_t)(q0w + l31) * DK + ks * 16 + hi8]);

    f32x16 o0 = {0.f,0.f,0.f,0.f,0.f,0.f,0.f,0.f,0.f,0.f,0.f,0.f,0.f,0.f,0.f,0.f};
    f32x16 o1 = o0;
    float m = -3.0e38f;
    float lsum = 0.f;

    // K staging: 4 chunks/thread (c = j*128 + tid), pre-swizzled source cols
    int rr[4], cbk[4];
#pragma unroll
    for (int j = 0; j < 4; ++j) {
        int c = j * 128 + tid;
        rr[j] = c >> 3;
        cbk[j] = ((c & 7) ^ (rr[j] & 7)) * 8;
    }
    auto kstage = [&](int buf, int n0_) {
#pragma unroll
        for (int j = 0; j < 4; ++j)
            gll16(Kh + (size_t)(n0_ + rr[j]) * DK + cbk[j], &Kls[buf][j * 1024 + w * 512]);
    };

    bf16x8 v00[2], v01[2], v10[2], v11[2];   // V frags of current tile
    U8 pf0[2], pf1[2];                        // P frags of previous tile

    kstage(0, 0);

    for (int t = 0; t < ntb; ++t) {
        VMCNT(0);
        BAR();
        SFENCE();
        if (t + 1 < ntb) kstage((t + 1) & 1, (t + 1) * 64);

        const int n0 = t * 64;
        const short* Kc = Kls[t & 1];

        // ---- QK(t): MFMA (independent of PV(t-1))
        f32x16 s0 = {0.f,0.f,0.f,0.f,0.f,0.f,0.f,0.f,0.f,0.f,0.f,0.f,0.f,0.f,0.f,0.f};
        f32x16 s1 = s0;
        __builtin_amdgcn_s_setprio(1);
#pragma unroll
        for (int ks = 0; ks < 4; ++ks) {
            bf16x8 kf0 = lds_frag(Kc, l31,      ks * 2 + hi);
            bf16x8 kf1 = lds_frag(Kc, 32 + l31, ks * 2 + hi);
            s0 = __builtin_amdgcn_mfma_f32_32x32x16_bf16(kf0, qf[ks], s0, 0, 0, 0);
            s1 = __builtin_amdgcn_mfma_f32_32x32x16_bf16(kf1, qf[ks], s1, 0, 0, 0);
        }
        // ---- PV(t-1): MFMA overlaps softmax(t) on the VALU
        if (t > 0) {
#pragma unroll
            for (int kb = 0; kb < 2; ++kb) {
                o0 = __builtin_amdgcn_mfma_f32_32x32x16_bf16(pf0[kb].v, v00[kb], o0, 0, 0, 0);
                o0 = __builtin_amdgcn_mfma_f32_32x32x16_bf16(pf1[kb].v, v01[kb], o0, 0, 0, 0);
                o1 = __builtin_amdgcn_mfma_f32_32x32x16_bf16(pf0[kb].v, v10[kb], o1, 0, 0, 0);
                o1 = __builtin_amdgcn_mfma_f32_32x32x16_bf16(pf1[kb].v, v11[kb], o1, 0, 0, 0);
            }
        }
        __builtin_amdgcn_s_setprio(0);

        // ---- V(t) -> registers (coalesced tiled layout; consumed at PV(t) next iter)
        const short* vt = Vh + (size_t)t * 4096;
#pragma unroll
        for (int kb = 0; kb < 2; ++kb) {
            v00[kb] = *reinterpret_cast<const bf16x8*>(vt + (kb * 4 + hi) * 512 + l31 * 8);
            v01[kb] = *reinterpret_cast<const bf16x8*>(vt + (kb * 4 + 2 + hi) * 512 + l31 * 8);
            v10[kb] = *reinterpret_cast<const bf16x8*>(vt + (kb * 4 + hi) * 512 + 256 + l31 * 8);
            v11[kb] = *reinterpret_cast<const bf16x8*>(vt + (kb * 4 + 2 + hi) * 512 + 256 + l31 * 8);
        }
        SFENCE();

        // ---- softmax(t) (VALU; overlaps the MFMAs issued above)
        float p[32];
#pragma unroll
        for (int r = 0; r < 16; ++r) { p[r] = s0[r]; p[16 + r] = s1[r]; }

        if (n0 + 64 > q0w) {
            const int qrel = q0w + l31 - n0;
#pragma unroll
            for (int r = 0; r < 16; ++r) {
                const int kvm = (r & 3) + 8 * (r >> 2) + hi4;
                if (kvm > qrel) p[r] = -3.0e38f;
                if (kvm + 32 > qrel) p[16 + r] = -3.0e38f;
            }
        }

        float t16[16];
#pragma unroll
        for (int r = 0; r < 16; ++r) t16[r] = fmaxf(p[r], p[16 + r]);
#pragma unroll
        for (int d = 8; d >= 1; d >>= 1)
#pragma unroll
            for (int r = 0; r < 8; ++r)
                if (r < d) t16[r] = fmaxf(t16[r], t16[r + d]);
        float tmax = fmaxf(t16[0], __shfl_xor(t16[0], 32));

        if (__any(tmax > m + 8.0f)) {     // rare (defer-max); waits on PV results — exact
            float mnew = fmaxf(m, tmax);
            float alpha = __builtin_amdgcn_exp2f(m - mnew);
            m = mnew;
#pragma unroll
            for (int r = 0; r < 16; ++r) {
                float ar = __shfl(alpha, (r & 3) + 8 * (r >> 2) + hi4);
                o0[r] *= ar; o1[r] *= ar;
            }
            lsum *= alpha;
        }

#pragma unroll
        for (int r = 0; r < 32; ++r) p[r] = __builtin_amdgcn_exp2f(p[r] - m);
        float a16[16];
#pragma unroll
        for (int r = 0; r < 16; ++r) a16[r] = p[r] + p[16 + r];
#pragma unroll
        for (int d = 8; d >= 1; d >>= 1)
#pragma unroll
            for (int r = 0; r < 8; ++r)
                if (r < d) a16[r] += a16[r + d];
        lsum += a16[0] + __shfl_xor(a16[0], 32);

        // ---- pack P(t) -> pf frags (consumed by PV(t) next iteration)
#pragma unroll
        for (int kb = 0; kb < 2; ++kb) {
            unsigned pk0 = pkbf16(p[kb * 16 + 0],  p[kb * 16 + 1]);
            unsigned pk1 = pkbf16(p[kb * 16 + 2],  p[kb * 16 + 3]);
            unsigned pk2 = pkbf16(p[kb * 16 + 4],  p[kb * 16 + 5]);
            unsigned pk3 = pkbf16(p[kb * 16 + 6],  p[kb * 16 + 7]);
            unsigned pk4 = pkbf16(p[kb * 16 + 8],  p[kb * 16 + 9]);
            unsigned pk5 = pkbf16(p[kb * 16 + 10], p[kb * 16 + 11]);
            unsigned pk6 = pkbf16(p[kb * 16 + 12], p[kb * 16 + 13]);
            unsigned pk7 = pkbf16(p[kb * 16 + 14], p[kb * 16 + 15]);
            pl32swap(pk0, pk2); pl32swap(pk1, pk3);
            pl32swap(pk4, pk6); pl32swap(pk5, pk7);
            pf0[kb].u[0] = pk0; pf0[kb].u[1] = pk1; pf0[kb].u[2] = pk2; pf0[kb].u[3] = pk3;
            pf1[kb].u[0] = pk4; pf1[kb].u[1] = pk5; pf1[kb].u[2] = pk6; pf1[kb].u[3] = pk7;
        }
    }

    // ---- final PV (last tile)
    __builtin_amdgcn_s_setprio(1);
#pragma unroll
    for (int kb = 0; kb < 2; ++kb) {
        o0 = __builtin_amdgcn_mfma_f32_32x32x16_bf16(pf0[kb].v, v00[kb], o0, 0, 0, 0);
        o0 = __builtin_amdgcn_mfma_f32_32x32x16_bf16(pf1[kb].v, v01[kb], o0, 0, 0, 0);
        o1 = __builtin_amdgcn_mfma_f32_32x32x16_bf16(pf0[kb].v, v10[kb], o1, 0, 0, 0);
        o1 = __builtin_amdgcn_mfma_f32_32x32x16_bf16(pf1[kb].v, v11[kb], o1, 0, 0, 0);
    }
    __builtin_amdgcn_s_setprio(0);

    // ---- epilogue: normalize, write Cc in TILED layout for gemm_out staging
    const int b = bh >> 4, h = bh & 15;
    const float linv = 1.0f / lsum;
#pragma unroll
    for (int r = 0; r < 16; ++r) {
        const int qoff = (r & 3) + 8 * (r >> 2) + hi4;
        float inv = __shfl(linv, qoff);
        const int mg = b * T_SEQ + q0w + qoff;
        const int mb = mg >> 7, row = mg & 127;
        const int kblk = l31 >> 3, el = l & 7;
        Cc[((size_t)(mb * 32 + h * 2 + 0)) * 4096 + kblk * 1024 + row * 8 + el] = f2b(o0[r] * inv);
        Cc[((size_t)(mb * 32 + h * 2 + 1)) * 4096 + kblk * 1024 + row * 8 + el] = f2b(o1[r] * inv);
    }
}

// ---------------- GEMM2: out = concat * W_out^T (fp32 store) ----------------
__global__ __launch_bounds__(256, 3) void gemm_out(const short* __restrict__ ab,
                                                   const short* __restrict__ wb,
                                                   float* __restrict__ out) {
    __shared__ short SM[3][6144];   // [buf][ A:0..4096 | B:4096..6144 ]
    const int tid = threadIdx.x;
    const int w = tid >> 6, l = tid & 63, lg = l >> 4, li = l & 15;
    const int wr = w >> 1, wc = w & 1;
    const int bn = blockIdx.x * 64, bm = blockIdx.y * 128;

    const short* pA = ab + (size_t)blockIdx.y * 32 * 4096 + (w * 128 + l) * 8;
    const short* pB = wb + (size_t)blockIdx.x * 32 * 2048 + (w * 64 + l) * 8;

    f32x4 zero = {0.f, 0.f, 0.f, 0.f};
    f32x4 acc[4][2];
#pragma unroll
    for (int m = 0; m < 4; ++m)
#pragma unroll
        for (int n = 0; n < 2; ++n) acc[m][n] = zero;

#define OSTAGE(buf, t_)                                                  \
    do {                                                                 \
        gll16(pA + (size_t)(t_) * 4096,       &SM[buf][w * 1024]);       \
        gll16(pA + (size_t)(t_) * 4096 + 512, &SM[buf][w * 1024 + 512]); \
        gll16(pB + (size_t)(t_) * 2048,       &SM[buf][4096 + w * 512]); \
    } while (0)

    OSTAGE(0, 0);
    OSTAGE(1, 1);

    for (int t = 0; t < 32; ++t) {
        if (t < 31) { VMCNT(3); } else { VMCNT(0); }
        BAR();
        SFENCE();
        if (t + 2 < 32) OSTAGE((t + 2) % 3, t + 2);
        const short* Ac = &SM[t % 3][0];
        const short* Bc = &SM[t % 3][4096];
        bf16x8 a[4], b[2];
#pragma unroll
        for (int m = 0; m < 4; ++m)
            a[m] = *reinterpret_cast<const bf16x8*>(&Ac[lg * 1024 + (wr * 64 + m * 16 + li) * 8]);
#pragma unroll
        for (int n = 0; n < 2; ++n)
            b[n] = *reinterpret_cast<const bf16x8*>(&Bc[lg * 512 + (wc * 32 + n * 16 + li) * 8]);
        __builtin_amdgcn_s_setprio(1);
#pragma unroll
        for (int m = 0; m < 4; ++m)
#pragma unroll
            for (int n = 0; n < 2; ++n)
                acc[m][n] = __builtin_amdgcn_mfma_f32_16x16x32_bf16(a[m], b[n], acc[m][n], 0, 0, 0);
        __builtin_amdgcn_s_setprio(0);
    }
#undef OSTAGE

#pragma unroll
    for (int m = 0; m < 4; ++m)
#pragma unroll
        for (int n = 0; n < 2; ++n)
#pragma unroll
            for (int r = 0; r < 4; ++r) {
                const int mi = bm + wr * 64 + m * 16 + lg * 4 + r;
                out[(size_t)mi * D_MODEL + bn + wc * 32 + n * 16 + li] = acc[m][n][r];
            }
}

extern "C" void kernel_launch(void* const* d_in, const int* in_sizes, int n_in,
                              void* d_out, int out_size, void* d_ws, size_t ws_size,
                              hipStream_t stream) {
    const float* x    = (const float*)d_in[0];
    const int*   pos  = (const int*)d_in[1];
    const float* wqkv = (const float*)d_in[2];
    const float* wout = (const float*)d_in[3];
    float* out = (float*)d_out;

    char* ws = (char*)d_ws;
    size_t off = 0;
    short* xb  = (short*)(ws + off); off += (size_t)4096 * 1024 * 2;      // 8 MB
    short* wqb = (short*)(ws + off); off += (size_t)3072 * 1024 * 2;      // 6 MB
    short* wob = (short*)(ws + off); off += (size_t)1024 * 1024 * 2;      // 2 MB
    short* Q   = (short*)(ws + off); off += (size_t)32 * 2048 * 64 * 2;   // 8 MB
    short* Kb  = (short*)(ws + off); off += (size_t)32 * 2048 * 64 * 2;   // 8 MB
    short* Vt  = (short*)(ws + off); off += (size_t)32 * 32 * 4096 * 2;   // 8 MB (tiled)
    off += 4096;
    short* Cc  = (short*)(ws + off); off += (size_t)4096 * 1024 * 2;      // 8 MB
    float* ct  = (float*)(ws + off); off += (size_t)4096 * 32 * 4;        // 0.5 MB
    float* st  = (float*)(ws + off); off += (size_t)4096 * 32 * 4;        // 0.5 MB

    cvt_all<<<4608, 256, 0, stream>>>(x, wqkv, wout, pos, xb, wqb, wob, ct, st);
    gemm_qkv<<<dim3(24, 32), 256, 0, stream>>>(xb, wqb, ct, st, Q, Kb, Vt);
    attn<<<1024, 128, 0, stream>>>(Q, Kb, Vt, Cc);
    gemm_out<<<dim3(16, 32), 256, 0, stream>>>(Cc, wob, out);
}

// Round 14
// 113.697 us; speedup vs baseline: 1.6440x; 1.6440x over previous
//
#include <hip/hip_runtime.h>
#include <hip/hip_bf16.h>
#include <cmath>

#define T_SEQ 2048
#define D_MODEL 1024
#define NHEAD 16
#define DK 64

typedef short bf16x8 __attribute__((ext_vector_type(8)));
typedef float f32x4 __attribute__((ext_vector_type(4)));
typedef float f32x16 __attribute__((ext_vector_type(16)));
typedef unsigned uint2v __attribute__((ext_vector_type(2)));

union U8 { unsigned u[4]; bf16x8 v; };

#define VMCNT(n) asm volatile("s_waitcnt vmcnt(" #n ")" ::: "memory")
#define BAR() __builtin_amdgcn_s_barrier()
#define SFENCE() __builtin_amdgcn_sched_barrier(0)

// RNE float -> bf16 (finite inputs only)
__device__ __forceinline__ short f2b(float f) {
    unsigned u = __builtin_bit_cast(unsigned, f);
    unsigned r = (u + 0x7FFFu + ((u >> 16) & 1u)) >> 16;
    return (short)r;
}

// async global->LDS, 16B per lane; lds base wave-uniform (HW adds lane*16)
__device__ __forceinline__ void gll16(const void* g, void* l) {
    __builtin_amdgcn_global_load_lds(
        (__attribute__((address_space(1))) void*)g,
        (__attribute__((address_space(3))) void*)l, 16, 0, 0);
}

// XOR-swizzled LDS frag read: row stride 128B, 16B chunk index 0..7
__device__ __forceinline__ bf16x8 lds_frag(const short* base, int row, int chunk) {
    return *reinterpret_cast<const bf16x8*>(
        (const char*)base + row * 128 + ((chunk * 16) ^ ((row & 7) << 4)));
}

__device__ __forceinline__ unsigned pkbf16(float a, float b) {
    unsigned r;
    asm("v_cvt_pk_bf16_f32 %0, %1, %2" : "=v"(r) : "v"(a), "v"(b));
    return r;
}
__device__ __forceinline__ void pl32swap(unsigned& a, unsigned& b) {
    uint2v r = __builtin_amdgcn_permlane32_swap(a, b, false, false);
    a = r.x; b = r.y;
}

// ====== fused fp32->bf16 convert into TILED layouts + RoPE table (one launch) ======
__global__ __launch_bounds__(256) void cvt_all(const float* __restrict__ x,
                                               const float* __restrict__ wq,
                                               const float* __restrict__ wo,
                                               const int* __restrict__ pos,
                                               short* __restrict__ xb,
                                               short* __restrict__ wqb,
                                               short* __restrict__ wob,
                                               float* __restrict__ ct,
                                               float* __restrict__ st) {
    int i = blockIdx.x * 256 + threadIdx.x;
    if (i >= 1048576) {                 // RoPE table: 131072 entries
        int j = i - 1048576;
        int bt = j >> 5, n = j & 31;
        float p = (float)pos[bt];
        float invf = expf((float)n * (-2.0f / (float)DK) * 9.210340371976184f);
        float s, c;
        sincosf(p * invf, &s, &c);
        ct[j] = c; st[j] = s;
        return;
    }
    const float* src;
    short* dst;
    int srcoff, c;
    if (i < 524288) {                 // xb: 32 rb x 32 kb tiles (128-row)
        c = i;
        int tile = c >> 9, cc = c & 511;
        int kblk = cc >> 7, row = cc & 127;
        int rb = tile >> 5, kb = tile & 31;
        srcoff = (rb * 128 + row) * D_MODEL + kb * 32 + kblk * 8;
        src = x; dst = xb;
    } else if (i < 917504) {          // wqb: 24 nb x 32 kb tiles (128-row)
        c = i - 524288;
        int tile = c >> 9, cc = c & 511;
        int kblk = cc >> 7, row = cc & 127;
        int rb = tile >> 5, kb = tile & 31;
        srcoff = (rb * 128 + row) * D_MODEL + kb * 32 + kblk * 8;
        src = wq; dst = wqb;
    } else {                          // wob: 16 nb x 32 kb tiles (64-row)
        c = i - 917504;
        int tile = c >> 8, cc = c & 255;
        int kblk = cc >> 6, row = cc & 63;
        int nb = tile >> 5, kb = tile & 31;
        srcoff = (nb * 64 + row) * D_MODEL + kb * 32 + kblk * 8;
        src = wo; dst = wob;
    }
    float4 a = *reinterpret_cast<const float4*>(src + srcoff);
    float4 b = *reinterpret_cast<const float4*>(src + srcoff + 4);
    bf16x8 v;
    v[0] = f2b(a.x); v[1] = f2b(a.y); v[2] = f2b(a.z); v[3] = f2b(a.w);
    v[4] = f2b(b.x); v[5] = f2b(b.y); v[6] = f2b(b.z); v[7] = f2b(b.w);
    reinterpret_cast<bf16x8*>(dst)[c] = v;
}

// ---------------- GEMM1: qkv = x * W_qkv^T, fused RoPE, scatter ----------------
// V written in per-(head,kvtile) tiles [ch(8)][d(64)][8] for coalesced PV loads.
__global__ __launch_bounds__(256, 3) void gemm_qkv(const short* __restrict__ xb,
                                                   const short* __restrict__ wb,
                                                   const float* __restrict__ ct,
                                                   const float* __restrict__ st,
                                                   short* __restrict__ Qo,
                                                   short* __restrict__ Ko,
                                                   short* __restrict__ Vt) {
    __shared__ short SM[3][8192];   // [buf][ A:0..4096 | B:4096..8192 ]
    const int tid = threadIdx.x;
    const int w = tid >> 6, l = tid & 63, lg = l >> 4, li = l & 15;
    const int wr = w >> 1, wc = w & 1;
    const int bn = blockIdx.x * 128, bm = blockIdx.y * 128;

    const short* pA = xb + (size_t)blockIdx.y * 32 * 4096 + (w * 128 + l) * 8;
    const short* pB = wb + (size_t)blockIdx.x * 32 * 4096 + (w * 128 + l) * 8;

    f32x4 zero = {0.f, 0.f, 0.f, 0.f};
    f32x4 acc[4][4];
#pragma unroll
    for (int m = 0; m < 4; ++m)
#pragma unroll
        for (int n = 0; n < 4; ++n) acc[m][n] = zero;

#define GSTAGE(buf, t_)                                               \
    do {                                                              \
        const size_t ko = (size_t)(t_) * 4096;                        \
        gll16(pA + ko,       &SM[buf][w * 1024]);                     \
        gll16(pA + ko + 512, &SM[buf][w * 1024 + 512]);               \
        gll16(pB + ko,       &SM[buf][4096 + w * 1024]);              \
        gll16(pB + ko + 512, &SM[buf][4096 + w * 1024 + 512]);        \
    } while (0)

    GSTAGE(0, 0);
    GSTAGE(1, 1);

    for (int t = 0; t < 32; ++t) {
        if (t < 31) { VMCNT(4); } else { VMCNT(0); }
        BAR();
        SFENCE();
        if (t + 2 < 32) GSTAGE((t + 2) % 3, t + 2);
        const short* Ac = &SM[t % 3][0];
        const short* Bc = &SM[t % 3][4096];
        bf16x8 a[4], b[4];
#pragma unroll
        for (int m = 0; m < 4; ++m)
            a[m] = *reinterpret_cast<const bf16x8*>(&Ac[lg * 1024 + (wr * 64 + m * 16 + li) * 8]);
#pragma unroll
        for (int n = 0; n < 4; ++n)
            b[n] = *reinterpret_cast<const bf16x8*>(&Bc[lg * 1024 + (wc * 64 + n * 16 + li) * 8]);
        __builtin_amdgcn_s_setprio(1);
#pragma unroll
        for (int m = 0; m < 4; ++m)
#pragma unroll
            for (int n = 0; n < 4; ++n)
                acc[m][n] = __builtin_amdgcn_mfma_f32_16x16x32_bf16(a[m], b[n], acc[m][n], 0, 0, 0);
        __builtin_amdgcn_s_setprio(0);
    }
#undef GSTAGE

    const int which = bn >> 10;                 // 0:q 1:k 2:v
    const int h = ((bn >> 6) + wc) & 15;
    if (which == 2) {
        // V: transpose via per-wave 8KB LDS scratch, write [ch][d][8] tiles
        __syncthreads();
        short* scr = &SM[0][0] + w * 4096;      // [d(64)][t(64)] swizzled, 8KB
#pragma unroll
        for (int n = 0; n < 4; ++n)
#pragma unroll
            for (int m = 0; m < 4; ++m)
#pragma unroll
                for (int rp = 0; rp < 2; ++rp) {
                    int d = n * 16 + li;
                    int t64 = m * 16 + lg * 4 + rp * 2;
                    unsigned pk = pkbf16(acc[m][n][rp * 2], acc[m][n][rp * 2 + 1]);
                    *reinterpret_cast<unsigned*>(
                        (char*)scr + ((d * 128 + t64 * 2) ^ ((d & 7) << 4))) = pk;
                }
        const int mi0 = bm + wr * 64;
        const int b0 = mi0 >> 11, t0 = mi0 & (T_SEQ - 1);
        const int kvt = t0 >> 6;
        short* vbase = Vt + ((size_t)(b0 * NHEAD + h) * 32 + kvt) * 4096;
        const int ch = l >> 3;
#pragma unroll
        for (int db = 0; db < 8; ++db) {
            int d = db * 8 + (l & 7);
            bf16x8 v = *reinterpret_cast<const bf16x8*>(
                (char*)scr + ((d * 128 + ch * 16) ^ ((d & 7) << 4)));
            *reinterpret_cast<bf16x8*>(vbase + ch * 512 + d * 8) = v;
        }
    } else {
#pragma unroll
        for (int n = 0; n < 4; ++n) {
            const int d = n * 16 + li;
#pragma unroll
            for (int m = 0; m < 4; ++m)
#pragma unroll
                for (int r = 0; r < 4; ++r) {
                    const int mi = bm + wr * 64 + m * 16 + lg * 4 + r;
                    const int b_ = mi >> 11, tt = mi & (T_SEQ - 1);
                    float v = acc[m][n][r];
                    float vp = __shfl_xor(v, 1);
                    int nn = n * 8 + (li >> 1);
                    float c = ct[(size_t)mi * 32 + nn];
                    float s = st[(size_t)mi * 32 + nn];
                    float o = (d & 1) ? (v * c + vp * s) : (v * c - vp * s);
                    if (which == 0) o *= 0.18033688011112042f;
                    short* dst = (which == 0) ? Qo : Ko;
                    dst[((size_t)((b_ * NHEAD + h) * T_SEQ + tt)) * DK + d] = f2b(o);
                }
        }
    }
}

// ------- flash attention (causal): counted-vmcnt pipeline, V prefetch 1 tile ahead ---
// 512 blocks x 256 thr, balanced qtile pairing; wave w owns rows [qt*128+32w, +32).
// K: 3-buffer LDS ring staged 2 tiles ahead (VMCNT(2) at loop top leaves next stage
// in flight). V: register double-buffer (vA/vB via unroll-by-2; ntb always even),
// loaded 1 full tile before PV consumes it. PV(t) in-tile; no cross-iter P state.
__global__ __launch_bounds__(256, 2) void attn(const short* __restrict__ Q,
                                               const short* __restrict__ K,
                                               const short* __restrict__ Vt,
                                               short* __restrict__ Cc) {
    __shared__ short Kls[3][4096];

    const int bid = blockIdx.x;
    const int ii = bid & 255, rhalf = bid >> 8;
    const int bh = ii & 31;
    const int qt = rhalf ? 15 - (ii >> 5) : (ii >> 5);
    const int ntb = 2 * qt + 2;               // always even

    const int tid = threadIdx.x;
    const int w = tid >> 6, l = tid & 63;
    const int l31 = l & 31, hi = l >> 5, hi4 = hi * 4, hi8 = hi * 8;
    const int q0w = qt * 128 + w * 32;
    const int Tw = (q0w + 32 + 63) >> 6;      // wave-active tiles: t < Tw

    const short* Qh = Q + (size_t)bh * T_SEQ * DK;
    const short* Kh = K + (size_t)bh * T_SEQ * DK;
    const short* Vh = Vt + (size_t)bh * 32 * 4096;

    bf16x8 qf[4];
#pragma unroll
    for (int ks = 0; ks < 4; ++ks)
        qf[ks] = *reinterpret_cast<const bf16x8*>(&Qh[(size_t)(q0w + l31) * DK + ks * 16 + hi8]);

    const f32x16 Z16 = {0.f,0.f,0.f,0.f,0.f,0.f,0.f,0.f,0.f,0.f,0.f,0.f,0.f,0.f,0.f,0.f};
    f32x16 o0 = Z16, o1 = Z16;
    float m = -3.0e38f;
    float lsum = 0.f;

    // K staging: 2 chunks/thread, pre-swizzled source cols
    int kr0, kc0, kr1, kc1;
    {
        int c0 = tid;        kr0 = c0 >> 3; kc0 = ((c0 & 7) ^ (kr0 & 7)) * 8;
        int c1 = 256 + tid;  kr1 = c1 >> 3; kc1 = ((c1 & 7) ^ (kr1 & 7)) * 8;
    }
#define KSTAGE(t_)                                                                     \
    do {                                                                               \
        gll16(Kh + (size_t)((t_) * 64 + kr0) * DK + kc0, &Kls[(t_) % 3][w * 512]);     \
        gll16(Kh + (size_t)((t_) * 64 + kr1) * DK + kc1, &Kls[(t_) % 3][2048 + w * 512]); \
    } while (0)

    // V fragment loads (coalesced [ch][d][8] tiled layout), 8 x 16B per thread
#define VLOAD(dst_, t_)                                                                \
    do {                                                                               \
        const short* vt = Vh + (size_t)(t_) * 4096;                                    \
        dst_[0] = *reinterpret_cast<const bf16x8*>(vt + (0 + hi) * 512 + l31 * 8);     \
        dst_[1] = *reinterpret_cast<const bf16x8*>(vt + (2 + hi) * 512 + l31 * 8);     \
        dst_[2] = *reinterpret_cast<const bf16x8*>(vt + (0 + hi) * 512 + 256 + l31 * 8); \
        dst_[3] = *reinterpret_cast<const bf16x8*>(vt + (2 + hi) * 512 + 256 + l31 * 8); \
        dst_[4] = *reinterpret_cast<const bf16x8*>(vt + (4 + hi) * 512 + l31 * 8);     \
        dst_[5] = *reinterpret_cast<const bf16x8*>(vt + (6 + hi) * 512 + l31 * 8);     \
        dst_[6] = *reinterpret_cast<const bf16x8*>(vt + (4 + hi) * 512 + 256 + l31 * 8); \
        dst_[7] = *reinterpret_cast<const bf16x8*>(vt + (6 + hi) * 512 + 256 + l31 * 8); \
    } while (0)

    // Per-tile compute: QK -> softmax -> pack -> PV (V frags already resident)
#define COMPUTE(t_, vv)                                                                \
    do {                                                                               \
        const int n0 = (t_) * 64;                                                      \
        const short* Kc = Kls[(t_) % 3];                                               \
        f32x16 s0 = Z16, s1 = Z16;                                                     \
        __builtin_amdgcn_s_setprio(1);                                                 \
        _Pragma("unroll")                                                              \
        for (int ks = 0; ks < 4; ++ks) {                                               \
            bf16x8 kf0 = lds_frag(Kc, l31,      ks * 2 + hi);                          \
            bf16x8 kf1 = lds_frag(Kc, 32 + l31, ks * 2 + hi);                          \
            s0 = __builtin_amdgcn_mfma_f32_32x32x16_bf16(kf0, qf[ks], s0, 0, 0, 0);    \
            s1 = __builtin_amdgcn_mfma_f32_32x32x16_bf16(kf1, qf[ks], s1, 0, 0, 0);    \
        }                                                                              \
        __builtin_amdgcn_s_setprio(0);                                                 \
        float p[32];                                                                   \
        _Pragma("unroll")                                                              \
        for (int r = 0; r < 16; ++r) { p[r] = s0[r]; p[16 + r] = s1[r]; }              \
        if (n0 + 64 > q0w) {                                                           \
            const int qrel = q0w + l31 - n0;                                           \
            _Pragma("unroll")                                                          \
            for (int r = 0; r < 16; ++r) {                                             \
                const int kvm = (r & 3) + 8 * (r >> 2) + hi4;                          \
                if (kvm > qrel) p[r] = -3.0e38f;                                       \
                if (kvm + 32 > qrel) p[16 + r] = -3.0e38f;                             \
            }                                                                          \
        }                                                                              \
        float t16[16];                                                                 \
        _Pragma("unroll")                                                              \
        for (int r = 0; r < 16; ++r) t16[r] = fmaxf(p[r], p[16 + r]);                  \
        _Pragma("unroll")                                                              \
        for (int d = 8; d >= 1; d >>= 1)                                               \
            _Pragma("unroll")                                                          \
            for (int r = 0; r < 8; ++r)                                                \
                if (r < d) t16[r] = fmaxf(t16[r], t16[r + d]);                         \
        float tmax = fmaxf(t16[0], __shfl_xor(t16[0], 32));                            \
        if (__any(tmax > m + 8.0f)) {                                                  \
            float mnew = fmaxf(m, tmax);                                               \
            float alpha = __builtin_amdgcn_exp2f(m - mnew);                            \
            m = mnew;                                                                  \
            _Pragma("unroll")                                                          \
            for (int r = 0; r < 16; ++r) {                                             \
                float ar = __shfl(alpha, (r & 3) + 8 * (r >> 2) + hi4);                \
                o0[r] *= ar; o1[r] *= ar;                                              \
            }                                                                          \
            lsum *= alpha;                                                             \
        }                                                                              \
        _Pragma("unroll")                                                              \
        for (int r = 0; r < 32; ++r) p[r] = __builtin_amdgcn_exp2f(p[r] - m);          \
        float a16[16];                                                                 \
        _Pragma("unroll")                                                              \
        for (int r = 0; r < 16; ++r) a16[r] = p[r] + p[16 + r];                        \
        _Pragma("unroll")                                                              \
        for (int d = 8; d >= 1; d >>= 1)                                               \
            _Pragma("unroll")                                                          \
            for (int r = 0; r < 8; ++r)                                                \
                if (r < d) a16[r] += a16[r + d];                                       \
        lsum += a16[0] + __shfl_xor(a16[0], 32);                                       \
        __builtin_amdgcn_s_setprio(1);                                                 \
        _Pragma("unroll")                                                              \
        for (int kb = 0; kb < 2; ++kb) {                                               \
            unsigned pk0 = pkbf16(p[kb * 16 + 0],  p[kb * 16 + 1]);                    \
            unsigned pk1 = pkbf16(p[kb * 16 + 2],  p[kb * 16 + 3]);                    \
            unsigned pk2 = pkbf16(p[kb * 16 + 4],  p[kb * 16 + 5]);                    \
            unsigned pk3 = pkbf16(p[kb * 16 + 6],  p[kb * 16 + 7]);                    \
            unsigned pk4 = pkbf16(p[kb * 16 + 8],  p[kb * 16 + 9]);                    \
            unsigned pk5 = pkbf16(p[kb * 16 + 10], p[kb * 16 + 11]);                   \
            unsigned pk6 = pkbf16(p[kb * 16 + 12], p[kb * 16 + 13]);                   \
            unsigned pk7 = pkbf16(p[kb * 16 + 14], p[kb * 16 + 15]);                   \
            pl32swap(pk0, pk2); pl32swap(pk1, pk3);                                    \
            pl32swap(pk4, pk6); pl32swap(pk5, pk7);                                    \
            U8 f0, f1;                                                                 \
            f0.u[0] = pk0; f0.u[1] = pk1; f0.u[2] = pk2; f0.u[3] = pk3;                \
            f1.u[0] = pk4; f1.u[1] = pk5; f1.u[2] = pk6; f1.u[3] = pk7;                \
            o0 = __builtin_amdgcn_mfma_f32_32x32x16_bf16(f0.v, vv[kb * 4 + 0], o0, 0, 0, 0); \
            o0 = __builtin_amdgcn_mfma_f32_32x32x16_bf16(f1.v, vv[kb * 4 + 1], o0, 0, 0, 0); \
            o1 = __builtin_amdgcn_mfma_f32_32x32x16_bf16(f0.v, vv[kb * 4 + 2], o1, 0, 0, 0); \
            o1 = __builtin_amdgcn_mfma_f32_32x32x16_bf16(f1.v, vv[kb * 4 + 3], o1, 0, 0, 0); \
        }                                                                              \
        __builtin_amdgcn_s_setprio(0);                                                 \
    } while (0)

    bf16x8 vA[8], vB[8];

    // prologue: V(0) first (oldest), then K stages for tiles 0 and 1
    VLOAD(vA, 0);
    KSTAGE(0);
    KSTAGE(1);

    for (int t = 0; t < ntb; t += 2) {
        // ---- even tile t: consumes vA, Kls[t%3]
        VMCNT(2);                         // waits V(t)+K(t); leaves K(t+1) in flight
        BAR();
        SFENCE();
        VLOAD(vB, t + 1);                 // V for odd tile (consumed next half-iter)
        if (t + 2 < ntb) KSTAGE(t + 2);
        if (t < Tw) COMPUTE(t, vA);
        // ---- odd tile t+1: consumes vB, Kls[(t+1)%3]
        VMCNT(2);                         // waits V(t+1)+K(t+1); leaves K(t+2)
        BAR();
        SFENCE();
        if (t + 2 < ntb) VLOAD(vA, t + 2);
        if (t + 3 < ntb) KSTAGE(t + 3);
        if (t + 1 < Tw) COMPUTE(t + 1, vB);
    }
#undef COMPUTE
#undef VLOAD
#undef KSTAGE

    // ---- epilogue: normalize, write Cc in TILED layout for gemm_out staging
    const int b = bh >> 4, h = bh & 15;
    const float linv = 1.0f / lsum;
#pragma unroll
    for (int r = 0; r < 16; ++r) {
        const int qoff = (r & 3) + 8 * (r >> 2) + hi4;
        float inv = __shfl(linv, qoff);
        const int mg = b * T_SEQ + q0w + qoff;
        const int mb = mg >> 7, row = mg & 127;
        const int kblk = l31 >> 3, el = l & 7;
        Cc[((size_t)(mb * 32 + h * 2 + 0)) * 4096 + kblk * 1024 + row * 8 + el] = f2b(o0[r] * inv);
        Cc[((size_t)(mb * 32 + h * 2 + 1)) * 4096 + kblk * 1024 + row * 8 + el] = f2b(o1[r] * inv);
    }
}

// ---------------- GEMM2: out = concat * W_out^T (fp32 store) ----------------
__global__ __launch_bounds__(256, 3) void gemm_out(const short* __restrict__ ab,
                                                   const short* __restrict__ wb,
                                                   float* __restrict__ out) {
    __shared__ short SM[3][6144];   // [buf][ A:0..4096 | B:4096..6144 ]
    const int tid = threadIdx.x;
    const int w = tid >> 6, l = tid & 63, lg = l >> 4, li = l & 15;
    const int wr = w >> 1, wc = w & 1;
    const int bn = blockIdx.x * 64, bm = blockIdx.y * 128;

    const short* pA = ab + (size_t)blockIdx.y * 32 * 4096 + (w * 128 + l) * 8;
    const short* pB = wb + (size_t)blockIdx.x * 32 * 2048 + (w * 64 + l) * 8;

    f32x4 zero = {0.f, 0.f, 0.f, 0.f};
    f32x4 acc[4][2];
#pragma unroll
    for (int m = 0; m < 4; ++m)
#pragma unroll
        for (int n = 0; n < 2; ++n) acc[m][n] = zero;

#define OSTAGE(buf, t_)                                                  \
    do {                                                                 \
        gll16(pA + (size_t)(t_) * 4096,       &SM[buf][w * 1024]);       \
        gll16(pA + (size_t)(t_) * 4096 + 512, &SM[buf][w * 1024 + 512]); \
        gll16(pB + (size_t)(t_) * 2048,       &SM[buf][4096 + w * 512]); \
    } while (0)

    OSTAGE(0, 0);
    OSTAGE(1, 1);

    for (int t = 0; t < 32; ++t) {
        if (t < 31) { VMCNT(3); } else { VMCNT(0); }
        BAR();
        SFENCE();
        if (t + 2 < 32) OSTAGE((t + 2) % 3, t + 2);
        const short* Ac = &SM[t % 3][0];
        const short* Bc = &SM[t % 3][4096];
        bf16x8 a[4], b[2];
#pragma unroll
        for (int m = 0; m < 4; ++m)
            a[m] = *reinterpret_cast<const bf16x8*>(&Ac[lg * 1024 + (wr * 64 + m * 16 + li) * 8]);
#pragma unroll
        for (int n = 0; n < 2; ++n)
            b[n] = *reinterpret_cast<const bf16x8*>(&Bc[lg * 512 + (wc * 32 + n * 16 + li) * 8]);
        __builtin_amdgcn_s_setprio(1);
#pragma unroll
        for (int m = 0; m < 4; ++m)
#pragma unroll
            for (int n = 0; n < 2; ++n)
                acc[m][n] = __builtin_amdgcn_mfma_f32_16x16x32_bf16(a[m], b[n], acc[m][n], 0, 0, 0);
        __builtin_amdgcn_s_setprio(0);
    }
#undef OSTAGE

#pragma unroll
    for (int m = 0; m < 4; ++m)
#pragma unroll
        for (int n = 0; n < 2; ++n)
#pragma unroll
            for (int r = 0; r < 4; ++r) {
                const int mi = bm + wr * 64 + m * 16 + lg * 4 + r;
                out[(size_t)mi * D_MODEL + bn + wc * 32 + n * 16 + li] = acc[m][n][r];
            }
}

extern "C" void kernel_launch(void* const* d_in, const int* in_sizes, int n_in,
                              void* d_out, int out_size, void* d_ws, size_t ws_size,
                              hipStream_t stream) {
    const float* x    = (const float*)d_in[0];
    const int*   pos  = (const int*)d_in[1];
    const float* wqkv = (const float*)d_in[2];
    const float* wout = (const float*)d_in[3];
    float* out = (float*)d_out;

    char* ws = (char*)d_ws;
    size_t off = 0;
    short* xb  = (short*)(ws + off); off += (size_t)4096 * 1024 * 2;      // 8 MB
    short* wqb = (short*)(ws + off); off += (size_t)3072 * 1024 * 2;      // 6 MB
    short* wob = (short*)(ws + off); off += (size_t)1024 * 1024 * 2;      // 2 MB
    short* Q   = (short*)(ws + off); off += (size_t)32 * 2048 * 64 * 2;   // 8 MB
    short* Kb  = (short*)(ws + off); off += (size_t)32 * 2048 * 64 * 2;   // 8 MB
    short* Vt  = (short*)(ws + off); off += (size_t)32 * 32 * 4096 * 2;   // 8 MB (tiled)
    off += 4096;
    short* Cc  = (short*)(ws + off); off += (size_t)4096 * 1024 * 2;      // 8 MB
    float* ct  = (float*)(ws + off); off += (size_t)4096 * 32 * 4;        // 0.5 MB
    float* st  = (float*)(ws + off); off += (size_t)4096 * 32 * 4;        // 0.5 MB

    cvt_all<<<4608, 256, 0, stream>>>(x, wqkv, wout, pos, xb, wqb, wob, ct, st);
    gemm_qkv<<<dim3(24, 32), 256, 0, stream>>>(xb, wqb, ct, st, Q, Kb, Vt);
    attn<<<512, 256, 0, stream>>>(Q, Kb, Vt, Cc);
    gemm_out<<<dim3(16, 32), 256, 0, stream>>>(Cc, wob, out);
}

// Round 15
// 111.231 us; speedup vs baseline: 1.6804x; 1.0222x over previous
//
#include <hip/hip_runtime.h>
#include <hip/hip_bf16.h>
#include <cmath>

#define T_SEQ 2048
#define D_MODEL 1024
#define NHEAD 16
#define DK 64

typedef short bf16x8 __attribute__((ext_vector_type(8)));
typedef float f32x4 __attribute__((ext_vector_type(4)));
typedef float f32x16 __attribute__((ext_vector_type(16)));
typedef unsigned uint2v __attribute__((ext_vector_type(2)));

union U8 { unsigned u[4]; bf16x8 v; };

#define VMCNT(n) asm volatile("s_waitcnt vmcnt(" #n ")" ::: "memory")
#define BAR() __builtin_amdgcn_s_barrier()
#define SFENCE() __builtin_amdgcn_sched_barrier(0)

// RNE float -> bf16 (finite inputs only)
__device__ __forceinline__ short f2b(float f) {
    unsigned u = __builtin_bit_cast(unsigned, f);
    unsigned r = (u + 0x7FFFu + ((u >> 16) & 1u)) >> 16;
    return (short)r;
}

// async global->LDS, 16B per lane; lds base wave-uniform (HW adds lane*16)
__device__ __forceinline__ void gll16(const void* g, void* l) {
    __builtin_amdgcn_global_load_lds(
        (__attribute__((address_space(1))) void*)g,
        (__attribute__((address_space(3))) void*)l, 16, 0, 0);
}

// XOR-swizzled LDS frag read: row stride 128B, 16B chunk index 0..7
__device__ __forceinline__ bf16x8 lds_frag(const short* base, int row, int chunk) {
    return *reinterpret_cast<const bf16x8*>(
        (const char*)base + row * 128 + ((chunk * 16) ^ ((row & 7) << 4)));
}

__device__ __forceinline__ unsigned pkbf16(float a, float b) {
    unsigned r;
    asm("v_cvt_pk_bf16_f32 %0, %1, %2" : "=v"(r) : "v"(a), "v"(b));
    return r;
}
__device__ __forceinline__ void pl32swap(unsigned& a, unsigned& b) {
    uint2v r = __builtin_amdgcn_permlane32_swap(a, b, false, false);
    a = r.x; b = r.y;
}

// ====== fused fp32->bf16 convert into TILED layouts + RoPE table (one launch) ======
__global__ __launch_bounds__(256) void cvt_all(const float* __restrict__ x,
                                               const float* __restrict__ wq,
                                               const float* __restrict__ wo,
                                               const int* __restrict__ pos,
                                               short* __restrict__ xb,
                                               short* __restrict__ wqb,
                                               short* __restrict__ wob,
                                               float* __restrict__ ct,
                                               float* __restrict__ st) {
    int i = blockIdx.x * 256 + threadIdx.x;
    if (i >= 1048576) {                 // RoPE table: 131072 entries
        int j = i - 1048576;
        int bt = j >> 5, n = j & 31;
        float p = (float)pos[bt];
        float invf = expf((float)n * (-2.0f / (float)DK) * 9.210340371976184f);
        float s, c;
        sincosf(p * invf, &s, &c);
        ct[j] = c; st[j] = s;
        return;
    }
    const float* src;
    short* dst;
    int srcoff, c;
    if (i < 524288) {                 // xb: 32 rb x 32 kb tiles (128-row)
        c = i;
        int tile = c >> 9, cc = c & 511;
        int kblk = cc >> 7, row = cc & 127;
        int rb = tile >> 5, kb = tile & 31;
        srcoff = (rb * 128 + row) * D_MODEL + kb * 32 + kblk * 8;
        src = x; dst = xb;
    } else if (i < 917504) {          // wqb: 24 nb x 32 kb tiles (128-row)
        c = i - 524288;
        int tile = c >> 9, cc = c & 511;
        int kblk = cc >> 7, row = cc & 127;
        int rb = tile >> 5, kb = tile & 31;
        srcoff = (rb * 128 + row) * D_MODEL + kb * 32 + kblk * 8;
        src = wq; dst = wqb;
    } else {                          // wob: 16 nb x 32 kb tiles (64-row)
        c = i - 917504;
        int tile = c >> 8, cc = c & 255;
        int kblk = cc >> 6, row = cc & 63;
        int nb = tile >> 5, kb = tile & 31;
        srcoff = (nb * 64 + row) * D_MODEL + kb * 32 + kblk * 8;
        src = wo; dst = wob;
    }
    float4 a = *reinterpret_cast<const float4*>(src + srcoff);
    float4 b = *reinterpret_cast<const float4*>(src + srcoff + 4);
    bf16x8 v;
    v[0] = f2b(a.x); v[1] = f2b(a.y); v[2] = f2b(a.z); v[3] = f2b(a.w);
    v[4] = f2b(b.x); v[5] = f2b(b.y); v[6] = f2b(b.z); v[7] = f2b(b.w);
    reinterpret_cast<bf16x8*>(dst)[c] = v;
}

// ---------------- GEMM1: qkv = x * W_qkv^T, fused RoPE, scatter ----------------
// V written in per-(head,kvtile) tiles [ch(8)][d(64)][8] for coalesced PV loads.
__global__ __launch_bounds__(256, 3) void gemm_qkv(const short* __restrict__ xb,
                                                   const short* __restrict__ wb,
                                                   const float* __restrict__ ct,
                                                   const float* __restrict__ st,
                                                   short* __restrict__ Qo,
                                                   short* __restrict__ Ko,
                                                   short* __restrict__ Vt) {
    __shared__ short SM[3][8192];   // [buf][ A:0..4096 | B:4096..8192 ]
    const int tid = threadIdx.x;
    const int w = tid >> 6, l = tid & 63, lg = l >> 4, li = l & 15;
    const int wr = w >> 1, wc = w & 1;
    const int bn = blockIdx.x * 128, bm = blockIdx.y * 128;

    const short* pA = xb + (size_t)blockIdx.y * 32 * 4096 + (w * 128 + l) * 8;
    const short* pB = wb + (size_t)blockIdx.x * 32 * 4096 + (w * 128 + l) * 8;

    f32x4 zero = {0.f, 0.f, 0.f, 0.f};
    f32x4 acc[4][4];
#pragma unroll
    for (int m = 0; m < 4; ++m)
#pragma unroll
        for (int n = 0; n < 4; ++n) acc[m][n] = zero;

#define GSTAGE(buf, t_)                                               \
    do {                                                              \
        const size_t ko = (size_t)(t_) * 4096;                        \
        gll16(pA + ko,       &SM[buf][w * 1024]);                     \
        gll16(pA + ko + 512, &SM[buf][w * 1024 + 512]);               \
        gll16(pB + ko,       &SM[buf][4096 + w * 1024]);              \
        gll16(pB + ko + 512, &SM[buf][4096 + w * 1024 + 512]);        \
    } while (0)

    GSTAGE(0, 0);
    GSTAGE(1, 1);

    for (int t = 0; t < 32; ++t) {
        if (t < 31) { VMCNT(4); } else { VMCNT(0); }
        BAR();
        SFENCE();
        if (t + 2 < 32) GSTAGE((t + 2) % 3, t + 2);
        const short* Ac = &SM[t % 3][0];
        const short* Bc = &SM[t % 3][4096];
        bf16x8 a[4], b[4];
#pragma unroll
        for (int m = 0; m < 4; ++m)
            a[m] = *reinterpret_cast<const bf16x8*>(&Ac[lg * 1024 + (wr * 64 + m * 16 + li) * 8]);
#pragma unroll
        for (int n = 0; n < 4; ++n)
            b[n] = *reinterpret_cast<const bf16x8*>(&Bc[lg * 1024 + (wc * 64 + n * 16 + li) * 8]);
        __builtin_amdgcn_s_setprio(1);
#pragma unroll
        for (int m = 0; m < 4; ++m)
#pragma unroll
            for (int n = 0; n < 4; ++n)
                acc[m][n] = __builtin_amdgcn_mfma_f32_16x16x32_bf16(a[m], b[n], acc[m][n], 0, 0, 0);
        __builtin_amdgcn_s_setprio(0);
    }
#undef GSTAGE

    const int which = bn >> 10;                 // 0:q 1:k 2:v
    const int h = ((bn >> 6) + wc) & 15;
    if (which == 2) {
        // V: transpose via per-wave 8KB LDS scratch, write [ch][d][8] tiles
        __syncthreads();
        short* scr = &SM[0][0] + w * 4096;      // [d(64)][t(64)] swizzled, 8KB
#pragma unroll
        for (int n = 0; n < 4; ++n)
#pragma unroll
            for (int m = 0; m < 4; ++m)
#pragma unroll
                for (int rp = 0; rp < 2; ++rp) {
                    int d = n * 16 + li;
                    int t64 = m * 16 + lg * 4 + rp * 2;
                    unsigned pk = pkbf16(acc[m][n][rp * 2], acc[m][n][rp * 2 + 1]);
                    *reinterpret_cast<unsigned*>(
                        (char*)scr + ((d * 128 + t64 * 2) ^ ((d & 7) << 4))) = pk;
                }
        const int mi0 = bm + wr * 64;
        const int b0 = mi0 >> 11, t0 = mi0 & (T_SEQ - 1);
        const int kvt = t0 >> 6;
        short* vbase = Vt + ((size_t)(b0 * NHEAD + h) * 32 + kvt) * 4096;
        const int ch = l >> 3;
#pragma unroll
        for (int db = 0; db < 8; ++db) {
            int d = db * 8 + (l & 7);
            bf16x8 v = *reinterpret_cast<const bf16x8*>(
                (char*)scr + ((d * 128 + ch * 16) ^ ((d & 7) << 4)));
            *reinterpret_cast<bf16x8*>(vbase + ch * 512 + d * 8) = v;
        }
    } else {
#pragma unroll
        for (int n = 0; n < 4; ++n) {
            const int d = n * 16 + li;
#pragma unroll
            for (int m = 0; m < 4; ++m)
#pragma unroll
                for (int r = 0; r < 4; ++r) {
                    const int mi = bm + wr * 64 + m * 16 + lg * 4 + r;
                    const int b_ = mi >> 11, tt = mi & (T_SEQ - 1);
                    float v = acc[m][n][r];
                    float vp = __shfl_xor(v, 1);
                    int nn = n * 8 + (li >> 1);
                    float c = ct[(size_t)mi * 32 + nn];
                    float s = st[(size_t)mi * 32 + nn];
                    float o = (d & 1) ? (v * c + vp * s) : (v * c - vp * s);
                    if (which == 0) o *= 0.18033688011112042f;
                    short* dst = (which == 0) ? Qo : Ko;
                    dst[((size_t)((b_ * NHEAD + h) * T_SEQ + tt)) * DK + d] = f2b(o);
                }
        }
    }
}

// ------- flash attention (causal): 128-row KV phases, 1 barrier per phase -------
// 512 blocks x 256 thr, balanced qtile pairing; wave w owns rows [qt*128+32w, +32).
// Phase p = KV tiles (2p, 2p+1). K: 2x16KB LDS ring, staged 1 phase ahead (VMCNT(16)
// at phase top drains only the K-stage, V loads stay in flight for compiler-counted
// waits). V: register double-buffer reloaded right after its consumer MFMAs.
__global__ __launch_bounds__(256, 2) void attn(const short* __restrict__ Q,
                                               const short* __restrict__ K,
                                               const short* __restrict__ Vt,
                                               short* __restrict__ Cc) {
    __shared__ short Kls[2][8192];   // 32 KB

    const int bid = blockIdx.x;
    const int ii = bid & 255, rhalf = bid >> 8;
    const int bh = ii & 31;
    const int qt = rhalf ? 15 - (ii >> 5) : (ii >> 5);
    const int nph = qt + 1;                   // phases of 128 KV rows

    const int tid = threadIdx.x;
    const int w = tid >> 6, l = tid & 63;
    const int l31 = l & 31, hi = l >> 5, hi4 = hi * 4, hi8 = hi * 8;
    const int q0w = qt * 128 + w * 32;
    const int Tw = (q0w + 32 + 63) >> 6;      // wave-active tiles: t < Tw

    const short* Qh = Q + (size_t)bh * T_SEQ * DK;
    const short* Kh = K + (size_t)bh * T_SEQ * DK;
    const short* Vh = Vt + (size_t)bh * 32 * 4096;

    bf16x8 qf[4];
#pragma unroll
    for (int ks = 0; ks < 4; ++ks)
        qf[ks] = *reinterpret_cast<const bf16x8*>(&Qh[(size_t)(q0w + l31) * DK + ks * 16 + hi8]);

    const f32x16 Z16 = {0.f,0.f,0.f,0.f,0.f,0.f,0.f,0.f,0.f,0.f,0.f,0.f,0.f,0.f,0.f,0.f};
    f32x16 o0 = Z16, o1 = Z16;
    float m = -3.0e38f;
    float lsum = 0.f;

    // K staging: 2 chunks/thread per 64-row tile, pre-swizzled source cols
    int kr0, kc0, kr1, kc1;
    {
        int c0 = tid;        kr0 = c0 >> 3; kc0 = ((c0 & 7) ^ (kr0 & 7)) * 8;
        int c1 = 256 + tid;  kr1 = c1 >> 3; kc1 = ((c1 & 7) ^ (kr1 & 7)) * 8;
    }
    // stage phase ph (tiles 2ph, 2ph+1) into Kls[ph&1]: 4 gll16
#define KSTAGE(ph)                                                                         \
    do {                                                                                   \
        const int b0_ = (ph) * 128;                                                        \
        gll16(Kh + (size_t)(b0_ + kr0) * DK + kc0,      &Kls[(ph) & 1][w * 512]);          \
        gll16(Kh + (size_t)(b0_ + kr1) * DK + kc1,      &Kls[(ph) & 1][2048 + w * 512]);   \
        gll16(Kh + (size_t)(b0_ + 64 + kr0) * DK + kc0, &Kls[(ph) & 1][4096 + w * 512]);   \
        gll16(Kh + (size_t)(b0_ + 64 + kr1) * DK + kc1, &Kls[(ph) & 1][4096 + 2048 + w * 512]); \
    } while (0)

    // V fragment loads (coalesced [ch][d][8] tiled layout), 8 x 16B per thread
#define VLOAD(dst_, t_)                                                                \
    do {                                                                               \
        const short* vt = Vh + (size_t)(t_) * 4096;                                    \
        dst_[0] = *reinterpret_cast<const bf16x8*>(vt + (0 + hi) * 512 + l31 * 8);     \
        dst_[1] = *reinterpret_cast<const bf16x8*>(vt + (2 + hi) * 512 + l31 * 8);     \
        dst_[2] = *reinterpret_cast<const bf16x8*>(vt + (0 + hi) * 512 + 256 + l31 * 8); \
        dst_[3] = *reinterpret_cast<const bf16x8*>(vt + (2 + hi) * 512 + 256 + l31 * 8); \
        dst_[4] = *reinterpret_cast<const bf16x8*>(vt + (4 + hi) * 512 + l31 * 8);     \
        dst_[5] = *reinterpret_cast<const bf16x8*>(vt + (6 + hi) * 512 + l31 * 8);     \
        dst_[6] = *reinterpret_cast<const bf16x8*>(vt + (4 + hi) * 512 + 256 + l31 * 8); \
        dst_[7] = *reinterpret_cast<const bf16x8*>(vt + (6 + hi) * 512 + 256 + l31 * 8); \
    } while (0)

    // Per-tile compute: QK -> softmax -> pack -> PV (V frags already resident)
#define COMPUTE(t_, vv)                                                                \
    do {                                                                               \
        const int n0 = (t_) * 64;                                                      \
        const short* Kc = &Kls[((t_) >> 1) & 1][((t_) & 1) * 4096];                    \
        f32x16 s0 = Z16, s1 = Z16;                                                     \
        __builtin_amdgcn_s_setprio(1);                                                 \
        _Pragma("unroll")                                                              \
        for (int ks = 0; ks < 4; ++ks) {                                               \
            bf16x8 kf0 = lds_frag(Kc, l31,      ks * 2 + hi);                          \
            bf16x8 kf1 = lds_frag(Kc, 32 + l31, ks * 2 + hi);                          \
            s0 = __builtin_amdgcn_mfma_f32_32x32x16_bf16(kf0, qf[ks], s0, 0, 0, 0);    \
            s1 = __builtin_amdgcn_mfma_f32_32x32x16_bf16(kf1, qf[ks], s1, 0, 0, 0);    \
        }                                                                              \
        __builtin_amdgcn_s_setprio(0);                                                 \
        float p[32];                                                                   \
        _Pragma("unroll")                                                              \
        for (int r = 0; r < 16; ++r) { p[r] = s0[r]; p[16 + r] = s1[r]; }              \
        if (n0 + 64 > q0w) {                                                           \
            const int qrel = q0w + l31 - n0;                                           \
            _Pragma("unroll")                                                          \
            for (int r = 0; r < 16; ++r) {                                             \
                const int kvm = (r & 3) + 8 * (r >> 2) + hi4;                          \
                if (kvm > qrel) p[r] = -3.0e38f;                                       \
                if (kvm + 32 > qrel) p[16 + r] = -3.0e38f;                             \
            }                                                                          \
        }                                                                              \
        float t16[16];                                                                 \
        _Pragma("unroll")                                                              \
        for (int r = 0; r < 16; ++r) t16[r] = fmaxf(p[r], p[16 + r]);                  \
        _Pragma("unroll")                                                              \
        for (int d = 8; d >= 1; d >>= 1)                                               \
            _Pragma("unroll")                                                          \
            for (int r = 0; r < 8; ++r)                                                \
                if (r < d) t16[r] = fmaxf(t16[r], t16[r + d]);                         \
        float tmax = fmaxf(t16[0], __shfl_xor(t16[0], 32));                            \
        if (__any(tmax > m + 8.0f)) {                                                  \
            float mnew = fmaxf(m, tmax);                                               \
            float alpha = __builtin_amdgcn_exp2f(m - mnew);                            \
            m = mnew;                                                                  \
            _Pragma("unroll")                                                          \
            for (int r = 0; r < 16; ++r) {                                             \
                float ar = __shfl(alpha, (r & 3) + 8 * (r >> 2) + hi4);                \
                o0[r] *= ar; o1[r] *= ar;                                              \
            }                                                                          \
            lsum *= alpha;                                                             \
        }                                                                              \
        _Pragma("unroll")                                                              \
        for (int r = 0; r < 32; ++r) p[r] = __builtin_amdgcn_exp2f(p[r] - m);          \
        float a16[16];                                                                 \
        _Pragma("unroll")                                                              \
        for (int r = 0; r < 16; ++r) a16[r] = p[r] + p[16 + r];                        \
        _Pragma("unroll")                                                              \
        for (int d = 8; d >= 1; d >>= 1)                                               \
            _Pragma("unroll")                                                          \
            for (int r = 0; r < 8; ++r)                                                \
                if (r < d) a16[r] += a16[r + d];                                       \
        lsum += a16[0] + __shfl_xor(a16[0], 32);                                       \
        __builtin_amdgcn_s_setprio(1);                                                 \
        _Pragma("unroll")                                                              \
        for (int kb = 0; kb < 2; ++kb) {                                               \
            unsigned pk0 = pkbf16(p[kb * 16 + 0],  p[kb * 16 + 1]);                    \
            unsigned pk1 = pkbf16(p[kb * 16 + 2],  p[kb * 16 + 3]);                    \
            unsigned pk2 = pkbf16(p[kb * 16 + 4],  p[kb * 16 + 5]);                    \
            unsigned pk3 = pkbf16(p[kb * 16 + 6],  p[kb * 16 + 7]);                    \
            unsigned pk4 = pkbf16(p[kb * 16 + 8],  p[kb * 16 + 9]);                    \
            unsigned pk5 = pkbf16(p[kb * 16 + 10], p[kb * 16 + 11]);                   \
            unsigned pk6 = pkbf16(p[kb * 16 + 12], p[kb * 16 + 13]);                   \
            unsigned pk7 = pkbf16(p[kb * 16 + 14], p[kb * 16 + 15]);                   \
            pl32swap(pk0, pk2); pl32swap(pk1, pk3);                                    \
            pl32swap(pk4, pk6); pl32swap(pk5, pk7);                                    \
            U8 f0, f1;                                                                 \
            f0.u[0] = pk0; f0.u[1] = pk1; f0.u[2] = pk2; f0.u[3] = pk3;                \
            f1.u[0] = pk4; f1.u[1] = pk5; f1.u[2] = pk6; f1.u[3] = pk7;                \
            o0 = __builtin_amdgcn_mfma_f32_32x32x16_bf16(f0.v, vv[kb * 4 + 0], o0, 0, 0, 0); \
            o0 = __builtin_amdgcn_mfma_f32_32x32x16_bf16(f1.v, vv[kb * 4 + 1], o0, 0, 0, 0); \
            o1 = __builtin_amdgcn_mfma_f32_32x32x16_bf16(f0.v, vv[kb * 4 + 2], o1, 0, 0, 0); \
            o1 = __builtin_amdgcn_mfma_f32_32x32x16_bf16(f1.v, vv[kb * 4 + 3], o1, 0, 0, 0); \
        }                                                                              \
        __builtin_amdgcn_s_setprio(0);                                                 \
    } while (0)

    bf16x8 vA[8], vB[8];

    // prologue: K(phase 0) FIRST (must be oldest for VMCNT(16)), then V(0), V(1)
    KSTAGE(0);
    SFENCE();
    VLOAD(vA, 0);
    VLOAD(vB, 1);

    for (int p = 0; p < nph; ++p) {
        VMCNT(16);                        // drains K(p) only; V loads stay in flight
        BAR();
        SFENCE();
        if (p + 1 < nph) KSTAGE(p + 1);   // next phase's K rides across the barrier
        SFENCE();
        const int t0 = 2 * p, t1 = 2 * p + 1;
        if (t0 < Tw) COMPUTE(t0, vA);
        if (p + 1 < nph) VLOAD(vA, t0 + 2);
        if (t1 < Tw) COMPUTE(t1, vB);
        if (p + 1 < nph) VLOAD(vB, t1 + 2);
    }
#undef COMPUTE
#undef VLOAD
#undef KSTAGE

    // ---- epilogue: normalize, write Cc in TILED layout for gemm_out staging
    const int b = bh >> 4, h = bh & 15;
    const float linv = 1.0f / lsum;
#pragma unroll
    for (int r = 0; r < 16; ++r) {
        const int qoff = (r & 3) + 8 * (r >> 2) + hi4;
        float inv = __shfl(linv, qoff);
        const int mg = b * T_SEQ + q0w + qoff;
        const int mb = mg >> 7, row = mg & 127;
        const int kblk = l31 >> 3, el = l & 7;
        Cc[((size_t)(mb * 32 + h * 2 + 0)) * 4096 + kblk * 1024 + row * 8 + el] = f2b(o0[r] * inv);
        Cc[((size_t)(mb * 32 + h * 2 + 1)) * 4096 + kblk * 1024 + row * 8 + el] = f2b(o1[r] * inv);
    }
}

// ---------------- GEMM2: out = concat * W_out^T (fp32 store) ----------------
__global__ __launch_bounds__(256, 3) void gemm_out(const short* __restrict__ ab,
                                                   const short* __restrict__ wb,
                                                   float* __restrict__ out) {
    __shared__ short SM[3][6144];   // [buf][ A:0..4096 | B:4096..6144 ]
    const int tid = threadIdx.x;
    const int w = tid >> 6, l = tid & 63, lg = l >> 4, li = l & 15;
    const int wr = w >> 1, wc = w & 1;
    const int bn = blockIdx.x * 64, bm = blockIdx.y * 128;

    const short* pA = ab + (size_t)blockIdx.y * 32 * 4096 + (w * 128 + l) * 8;
    const short* pB = wb + (size_t)blockIdx.x * 32 * 2048 + (w * 64 + l) * 8;

    f32x4 zero = {0.f, 0.f, 0.f, 0.f};
    f32x4 acc[4][2];
#pragma unroll
    for (int m = 0; m < 4; ++m)
#pragma unroll
        for (int n = 0; n < 2; ++n) acc[m][n] = zero;

#define OSTAGE(buf, t_)                                                  \
    do {                                                                 \
        gll16(pA + (size_t)(t_) * 4096,       &SM[buf][w * 1024]);       \
        gll16(pA + (size_t)(t_) * 4096 + 512, &SM[buf][w * 1024 + 512]); \
        gll16(pB + (size_t)(t_) * 2048,       &SM[buf][4096 + w * 512]); \
    } while (0)

    OSTAGE(0, 0);
    OSTAGE(1, 1);

    for (int t = 0; t < 32; ++t) {
        if (t < 31) { VMCNT(3); } else { VMCNT(0); }
        BAR();
        SFENCE();
        if (t + 2 < 32) OSTAGE((t + 2) % 3, t + 2);
        const short* Ac = &SM[t % 3][0];
        const short* Bc = &SM[t % 3][4096];
        bf16x8 a[4], b[2];
#pragma unroll
        for (int m = 0; m < 4; ++m)
            a[m] = *reinterpret_cast<const bf16x8*>(&Ac[lg * 1024 + (wr * 64 + m * 16 + li) * 8]);
#pragma unroll
        for (int n = 0; n < 2; ++n)
            b[n] = *reinterpret_cast<const bf16x8*>(&Bc[lg * 512 + (wc * 32 + n * 16 + li) * 8]);
        __builtin_amdgcn_s_setprio(1);
#pragma unroll
        for (int m = 0; m < 4; ++m)
#pragma unroll
            for (int n = 0; n < 2; ++n)
                acc[m][n] = __builtin_amdgcn_mfma_f32_16x16x32_bf16(a[m], b[n], acc[m][n], 0, 0, 0);
        __builtin_amdgcn_s_setprio(0);
    }
#undef OSTAGE

#pragma unroll
    for (int m = 0; m < 4; ++m)
#pragma unroll
        for (int n = 0; n < 2; ++n)
#pragma unroll
            for (int r = 0; r < 4; ++r) {
                const int mi = bm + wr * 64 + m * 16 + lg * 4 + r;
                out[(size_t)mi * D_MODEL + bn + wc * 32 + n * 16 + li] = acc[m][n][r];
            }
}

extern "C" void kernel_launch(void* const* d_in, const int* in_sizes, int n_in,
                              void* d_out, int out_size, void* d_ws, size_t ws_size,
                              hipStream_t stream) {
    const float* x    = (const float*)d_in[0];
    const int*   pos  = (const int*)d_in[1];
    const float* wqkv = (const float*)d_in[2];
    const float* wout = (const float*)d_in[3];
    float* out = (float*)d_out;

    char* ws = (char*)d_ws;
    size_t off = 0;
    short* xb  = (short*)(ws + off); off += (size_t)4096 * 1024 * 2;      // 8 MB
    short* wqb = (short*)(ws + off); off += (size_t)3072 * 1024 * 2;      // 6 MB
    short* wob = (short*)(ws + off); off += (size_t)1024 * 1024 * 2;      // 2 MB
    short* Q   = (short*)(ws + off); off += (size_t)32 * 2048 * 64 * 2;   // 8 MB
    short* Kb  = (short*)(ws + off); off += (size_t)32 * 2048 * 64 * 2;   // 8 MB
    short* Vt  = (short*)(ws + off); off += (size_t)32 * 32 * 4096 * 2;   // 8 MB (tiled)
    off += 4096;
    short* Cc  = (short*)(ws + off); off += (size_t)4096 * 1024 * 2;      // 8 MB
    float* ct  = (float*)(ws + off); off += (size_t)4096 * 32 * 4;        // 0.5 MB
    float* st  = (float*)(ws + off); off += (size_t)4096 * 32 * 4;        // 0.5 MB

    cvt_all<<<4608, 256, 0, stream>>>(x, wqkv, wout, pos, xb, wqb, wob, ct, st);
    gemm_qkv<<<dim3(24, 32), 256, 0, stream>>>(xb, wqb, ct, st, Q, Kb, Vt);
    attn<<<512, 256, 0, stream>>>(Q, Kb, Vt, Cc);
    gemm_out<<<dim3(16, 32), 256, 0, stream>>>(Cc, wob, out);
}